// Round 1
// baseline (824.319 us; speedup 1.0000x reference)
//
#include <hip/hip_runtime.h>
#include <hip/hip_bf16.h>

#define BATCH 16
#define SEQ   2048
#define DIM_  256

typedef __attribute__((ext_vector_type(8))) short short8;
typedef __attribute__((ext_vector_type(4))) float f32x4;
typedef __attribute__((ext_vector_type(4))) unsigned short ushort4v;

__device__ __forceinline__ unsigned short f2bf(float f) {
  union { __hip_bfloat16 h; unsigned short u; } cv;
  cv.h = __float2bfloat16(f);
  return cv.u;
}

// ---------------------------------------------------------------------------
// K1: S = QK^T * scale, softmax rows, write normalized attn (fp32).
// Block: one batch, 64 q-rows (4 waves x 16 rows). Two sweeps over k:
//   sweep 0: row sums of exp;  sweep 1: recompute S, write exp*inv_sum.
// ---------------------------------------------------------------------------
__global__ __launch_bounds__(256, 4)
void qk_softmax_kernel(const float* __restrict__ Q, const float* __restrict__ Km,
                       const int* __restrict__ if_draw_p, float* __restrict__ attn) {
  __shared__ unsigned short Kt[64 * 264];   // 64 k-rows x (256 + 8 pad) bf16
  const int b  = blockIdx.y;
  const int tid = threadIdx.x;
  const int w  = tid >> 6;
  const int l  = tid & 63;
  const int lr = l & 15;     // A row / B col / CD col
  const int lg = l >> 4;     // k-group
  const int q0 = blockIdx.x * 64 + w * 16;

  float scale = 0.0625f;                 // 1/sqrt(256)
  if (*if_draw_p != 0) scale *= 0.05f;   // / temperature 20

  // Hoist Q fragments: 16 rows x 256 k per wave -> 8 frags of 8 bf16
  short8 aq[8];
  {
    const float* qp = Q + ((size_t)b * SEQ + (size_t)(q0 + lr)) * DIM_ + lg * 8;
    #pragma unroll
    for (int t = 0; t < 8; ++t) {
      float4 x = *(const float4*)(qp + t * 32);
      float4 y = *(const float4*)(qp + t * 32 + 4);
      short8 a;
      a[0]=(short)f2bf(x.x); a[1]=(short)f2bf(x.y); a[2]=(short)f2bf(x.z); a[3]=(short)f2bf(x.w);
      a[4]=(short)f2bf(y.x); a[5]=(short)f2bf(y.y); a[6]=(short)f2bf(y.z); a[7]=(short)f2bf(y.w);
      aq[t] = a;
    }
  }

  const int sr = tid >> 2;           // staging row 0..63
  const int sc = (tid & 3) * 64;     // staging col base
  const float* kbase = Km + (size_t)b * SEQ * DIM_;

  float rsum[4] = {0.f, 0.f, 0.f, 0.f};
  float inv[4]  = {0.f, 0.f, 0.f, 0.f};

  for (int sweep = 0; sweep < 2; ++sweep) {
    if (sweep == 1) {
      #pragma unroll
      for (int i = 0; i < 4; ++i) {
        float s = rsum[i];
        s += __shfl_xor(s, 1);
        s += __shfl_xor(s, 2);
        s += __shfl_xor(s, 4);
        s += __shfl_xor(s, 8);
        inv[i] = 1.0f / s;
      }
    }
    for (int k0 = 0; k0 < SEQ; k0 += 64) {
      __syncthreads();
      { // stage K tile [64][256] fp32 -> bf16 LDS (padded rows)
        const float* kp = kbase + (size_t)(k0 + sr) * DIM_ + sc;
        unsigned short* dp = &Kt[sr * 264 + sc];
        #pragma unroll
        for (int i = 0; i < 16; ++i) {
          float4 x = *(const float4*)(kp + i * 4);
          ushort4v v;
          v[0]=f2bf(x.x); v[1]=f2bf(x.y); v[2]=f2bf(x.z); v[3]=f2bf(x.w);
          *(ushort4v*)(dp + i * 4) = v;
        }
      }
      __syncthreads();
      #pragma unroll
      for (int n = 0; n < 4; ++n) {
        f32x4 acc = {0.f, 0.f, 0.f, 0.f};
        const unsigned short* bp = &Kt[(n * 16 + lr) * 264 + lg * 8];
        #pragma unroll
        for (int t = 0; t < 8; ++t) {
          short8 bf = *(const short8*)(bp + t * 32);
          acc = __builtin_amdgcn_mfma_f32_16x16x32_bf16(aq[t], bf, acc, 0, 0, 0);
        }
        if (sweep == 0) {
          #pragma unroll
          for (int i = 0; i < 4; ++i) rsum[i] += __expf(acc[i] * scale);
        } else {
          float* op = attn + ((size_t)b * SEQ + (size_t)(q0 + lg * 4)) * SEQ
                    + (size_t)(k0 + n * 16 + lr);
          #pragma unroll
          for (int i = 0; i < 4; ++i)
            op[(size_t)i * SEQ] = __expf(acc[i] * scale) * inv[i];
        }
      }
    }
  }
}

// ---------------------------------------------------------------------------
// K2: ctx = attn @ V. attn A-frags straight from global; V staged transposed
// in LDS (row = d column, 64 k + 8 pad -> 144 B stride: bank-uniform b128).
// ---------------------------------------------------------------------------
__global__ __launch_bounds__(256, 3)
void pv_kernel(const float* __restrict__ attn, const float* __restrict__ V,
               float* __restrict__ ctx) {
  __shared__ unsigned short Vt[256 * 72];   // V^T tile: [d][64 k + 8 pad] bf16
  const int b  = blockIdx.y;
  const int tid = threadIdx.x;
  const int w  = tid >> 6;
  const int l  = tid & 63;
  const int lr = l & 15;
  const int lg = l >> 4;
  const int q0 = blockIdx.x * 64 + w * 16;

  f32x4 acc[16];
  #pragma unroll
  for (int n = 0; n < 16; ++n) acc[n] = (f32x4){0.f, 0.f, 0.f, 0.f};

  const float* vbase = V + (size_t)b * SEQ * DIM_;
  const float* abase = attn + ((size_t)b * SEQ + (size_t)(q0 + lr)) * SEQ;

  for (int k0 = 0; k0 < SEQ; k0 += 64) {
    __syncthreads();
    { // stage V^T: thread = one d column, 64 k values, 8x ds_write_b128
      const float* vp = vbase + (size_t)k0 * DIM_ + tid;
      unsigned short* dp = &Vt[tid * 72];
      #pragma unroll
      for (int kb = 0; kb < 8; ++kb) {
        short8 v;
        #pragma unroll
        for (int j = 0; j < 8; ++j)
          v[j] = (short)f2bf(vp[(kb * 8 + j) * DIM_]);
        *(short8*)(dp + kb * 8) = v;
      }
    }
    __syncthreads();
    #pragma unroll
    for (int kc = 0; kc < 2; ++kc) {
      const float* ap = abase + k0 + kc * 32 + lg * 8;
      float4 x = *(const float4*)ap;
      float4 y = *(const float4*)(ap + 4);
      short8 af;
      af[0]=(short)f2bf(x.x); af[1]=(short)f2bf(x.y); af[2]=(short)f2bf(x.z); af[3]=(short)f2bf(x.w);
      af[4]=(short)f2bf(y.x); af[5]=(short)f2bf(y.y); af[6]=(short)f2bf(y.z); af[7]=(short)f2bf(y.w);
      #pragma unroll
      for (int n = 0; n < 16; ++n) {
        short8 bf = *(const short8*)(&Vt[(n * 16 + lr) * 72 + kc * 32 + lg * 8]);
        acc[n] = __builtin_amdgcn_mfma_f32_16x16x32_bf16(af, bf, acc[n], 0, 0, 0);
      }
    }
  }

  float* cp = ctx + ((size_t)b * SEQ + (size_t)(q0 + lg * 4)) * DIM_ + lr;
  #pragma unroll
  for (int n = 0; n < 16; ++n) {
    #pragma unroll
    for (int i = 0; i < 4; ++i)
      cp[(size_t)i * DIM_ + n * 16] = acc[n][i];
  }
}

extern "C" void kernel_launch(void* const* d_in, const int* in_sizes, int n_in,
                              void* d_out, int out_size, void* d_ws, size_t ws_size,
                              hipStream_t stream) {
  const float* Q  = (const float*)d_in[0];
  const float* Kp = (const float*)d_in[1];
  const float* V  = (const float*)d_in[2];
  const int* if_draw = (const int*)d_in[4];

  float* ctx  = (float*)d_out;
  float* attn = (float*)d_out + (size_t)BATCH * SEQ * DIM_;

  dim3 grid(SEQ / 64, BATCH);
  dim3 blk(256);
  hipLaunchKernelGGL(qk_softmax_kernel, grid, blk, 0, stream, Q, Kp, if_draw, attn);
  hipLaunchKernelGGL(pv_kernel,        grid, blk, 0, stream, attn, V, ctx);
}